// Round 19
// baseline (185.732 us; speedup 1.0000x reference)
//
#include <hip/hip_runtime.h>
#include <hip/hip_bf16.h>
#include <math.h>

// ---------------------------------------------------------------------------
// DogeCDMoE round 19: EXACT round-18 file (passed, 181.4us) with ONE delta:
// gate/up GEMM tiles inside fused3 go 64x128 -> 128x128 (m93: bigger tile =
// more MFMA per barrier, ~517 vs ~340 TF). The old 1-block/CU objection to
// 256-block grids doesn't apply here: 2048 expert blocks keep CUs saturated.
// Grid 2560, pattern of 10 {4xE, G, 4xE, U}. Per-element K order unchanged
// -> gate/up bit-identical -> absmax stays exactly 0.01367188.
// ---------------------------------------------------------------------------

#define TOKENS 2048
#define DIM    1024
#define INTER  2048
#define NKEYS  128
#define TOPK   8
#define HEADS  4

typedef unsigned short ushort_t;
typedef __attribute__((ext_vector_type(8))) short bf16x8;
typedef __attribute__((ext_vector_type(4))) float f32x4;
typedef __attribute__((ext_vector_type(2))) float f32x2;

__device__ __forceinline__ float bf2f(ushort_t u) {
    unsigned int x = (unsigned int)u << 16;
    float f; __builtin_memcpy(&f, &x, 4); return f;
}
__device__ __forceinline__ ushort_t f2bf_rne(float f) {
    unsigned int x; __builtin_memcpy(&x, &f, 4);
    x += 0x7fffu + ((x >> 16) & 1u);
    return (ushort_t)(x >> 16);
}
__device__ __forceinline__ void gload_lds16(const void* g, void* l) {
    __builtin_amdgcn_global_load_lds(
        (const __attribute__((address_space(1))) unsigned int*)g,
        (__attribute__((address_space(3))) unsigned int*)l, 16, 0, 0);
}

// ---------------- fused f32 -> bf16 (RNE) for the 5 MFMA tensors ------------
__global__ __launch_bounds__(256) void convert_all(
    const float* __restrict__ h,  const float* __restrict__ wq,
    const float* __restrict__ wg, const float* __restrict__ wu,
    const float* __restrict__ wd,
    ushort_t* __restrict__ hb,  ushort_t* __restrict__ wqb,
    ushort_t* __restrict__ wgb, ushort_t* __restrict__ wub,
    ushort_t* __restrict__ wdb) {
    const int i = blockIdx.x * 256 + threadIdx.x;
    const float* src; ushort_t* dst; int off;
    if      (i <  262144) { src = h;  dst = hb;  off = i; }
    else if (i <  294912) { src = wq; dst = wqb; off = i - 262144; }
    else if (i <  557056) { src = wg; dst = wgb; off = i - 294912; }
    else if (i <  819200) { src = wu; dst = wub; off = i - 557056; }
    else                  { src = wd; dst = wdb; off = i - 819200; }
    const float4* p = (const float4*)src + (size_t)off * 2;
    const float4 a = p[0], b = p[1];
    uint4 o;
    o.x = (unsigned)f2bf_rne(a.x) | ((unsigned)f2bf_rne(a.y) << 16);
    o.y = (unsigned)f2bf_rne(a.z) | ((unsigned)f2bf_rne(a.w) << 16);
    o.z = (unsigned)f2bf_rne(b.x) | ((unsigned)f2bf_rne(b.y) << 16);
    o.w = (unsigned)f2bf_rne(b.z) | ((unsigned)f2bf_rne(b.w) << 16);
    ((uint4*)dst)[off] = o;
}

// ---------------- expert tables f32 -> fp8 e4m3 (x64 scale) -----------------
__global__ __launch_bounds__(256) void conv_tables(
    const float* __restrict__ de_f32, const float* __restrict__ ue_f32,
    unsigned* __restrict__ deb, unsigned* __restrict__ ueb) {
    const int id = blockIdx.x;                       // 0..16383
    const float* src = (id < 8192) ? de_f32 : ue_f32;
    unsigned*    dst = (id < 8192) ? deb : ueb;
    const size_t eoff = (size_t)(id & 8191) * 2048 + threadIdx.x * 8;
    const float4* p = (const float4*)(src + eoff);
    const float4 a = p[0], b = p[1];
    int w0 = 0, w1 = 0;
    w0 = __builtin_amdgcn_cvt_pk_fp8_f32(a.x * 64.f, a.y * 64.f, w0, false);
    w0 = __builtin_amdgcn_cvt_pk_fp8_f32(a.z * 64.f, a.w * 64.f, w0, true);
    w1 = __builtin_amdgcn_cvt_pk_fp8_f32(b.x * 64.f, b.y * 64.f, w1, false);
    w1 = __builtin_amdgcn_cvt_pk_fp8_f32(b.z * 64.f, b.w * 64.f, w1, true);
    *(uint2*)((char*)dst + eoff) = (uint2){(unsigned)w0, (unsigned)w1};
}

// ---------------- bf16 MFMA GEMM: C[M,N] = A[M,K] @ B[N,K]^T ----------------
// EPI 0: f32 = acc | 2: f32 = acc+extra_f32 (Cout may == extra) | 3: bf16
template<int BM, int BN, int WR, int WC, int FM, int FN, int EPI>
__global__ __launch_bounds__(256) void mfma_gemm(const ushort_t* __restrict__ A,
                                                 const ushort_t* __restrict__ B,
                                                 const void* __restrict__ extra,
                                                 void* __restrict__ Cout,
                                                 int M, int N, int K) {
    static_assert(WR * WC == 4 && WR * FM * 16 == BM && WC * FN * 16 == BN, "geom");
    __shared__ ushort_t As[BM * 32];
    __shared__ ushort_t Bs[BN * 32];
    const int tid = threadIdx.x;
    const int w = tid >> 6, lane = tid & 63;
    const int wr = w / WC, wc = w % WC;
    const int m0 = blockIdx.y * BM, n0 = blockIdx.x * BN;

    const int srow = (w << 4) + (lane >> 2);
    const int scol = (lane & 3) << 3;
    const ushort_t* Ag = &A[(size_t)(m0 + srow) * K + scol];
    const ushort_t* Bg = &B[(size_t)(n0 + srow) * K + scol];
    ushort_t* Al = &As[w << 9];
    ushort_t* Bl = &Bs[w << 9];

    const int frow = lane & 15;
    const int fcol = (lane >> 4) << 3;
    const ushort_t* Afr = &As[(size_t)(wr * FM * 16 + frow) * 32 + fcol];
    const ushort_t* Bfr = &Bs[(size_t)(wc * FN * 16 + frow) * 32 + fcol];

    f32x4 acc[FM][FN];
#pragma unroll
    for (int i = 0; i < FM; ++i)
#pragma unroll
        for (int j = 0; j < FN; ++j) acc[i][j] = (f32x4){0.f, 0.f, 0.f, 0.f};

    for (int k0 = 0; k0 < K; k0 += 32) {
        __syncthreads();
#pragma unroll
        for (int i = 0; i < BM / 64; ++i)
            gload_lds16(Ag + (size_t)i * 64 * K + k0, Al + i * 2048);
#pragma unroll
        for (int i = 0; i < BN / 64; ++i)
            gload_lds16(Bg + (size_t)i * 64 * K + k0, Bl + i * 2048);
        __syncthreads();

        bf16x8 af[FM], bfv[FN];
#pragma unroll
        for (int i = 0; i < FM; ++i) af[i] = *(const bf16x8*)(Afr + i * 512);
#pragma unroll
        for (int j = 0; j < FN; ++j) bfv[j] = *(const bf16x8*)(Bfr + j * 512);
#pragma unroll
        for (int i = 0; i < FM; ++i)
#pragma unroll
            for (int j = 0; j < FN; ++j)
                acc[i][j] = __builtin_amdgcn_mfma_f32_16x16x32_bf16(
                    af[i], bfv[j], acc[i][j], 0, 0, 0);
    }

    const int crow0 = m0 + wr * FM * 16 + ((lane >> 4) << 2);
    const int ccol0 = n0 + wc * FN * 16 + (lane & 15);
#pragma unroll
    for (int i = 0; i < FM; ++i)
#pragma unroll
        for (int j = 0; j < FN; ++j)
#pragma unroll
            for (int r = 0; r < 4; ++r) {
                const size_t off = (size_t)(crow0 + i * 16 + r) * N + ccol0 + j * 16;
                float v = acc[i][j][r];
                if (EPI == 2) {
                    ((float*)Cout)[off] = v + ((const float*)extra)[off];
                } else if (EPI == 3) {
                    ((ushort_t*)Cout)[off] = f2bf_rne(v);
                } else {
                    ((float*)Cout)[off] = v;
                }
            }
}

// ---------------- sims_tiled: key column in registers (R18-verified) --------
__global__ __launch_bounds__(256) void sims_tiled(const float* __restrict__ q,
                                                  const float* __restrict__ keys,
                                                  float* __restrict__ sims) {
    const int head = blockIdx.y;
    const int t0 = blockIdx.x * 16;
    const int p = threadIdx.x >> 7, k = threadIdx.x & 127;

    const float4* kc = (const float4*)&keys[(size_t)(((head << 7) | k) * 2 + p) * 32];
    float4 kv[8];
#pragma unroll
    for (int n = 0; n < 8; ++n) kv[n] = kc[n];

#pragma unroll 4
    for (int tt = 0; tt < 16; ++tt) {
        const int t = t0 + tt;
        const float4* qv = (const float4*)&q[(size_t)t * 256 + p * 128 + head * 32];
        float s = 0.f;
#pragma unroll
        for (int n = 0; n < 8; ++n) {
            const float4 a = qv[n], b = kv[n];
            s += a.x * b.x + a.y * b.y + a.z * b.z + a.w * b.w;
        }
        sims[(size_t)t * 1024 + head * 256 + p * 128 + k] = s;
    }
}

// ---------------- topk_select: rank-based on f32 sims (R16-18 verified) -----
__global__ __launch_bounds__(256) void topk_select(const float* __restrict__ sims,
                                                   int* __restrict__ eidx,
                                                   float* __restrict__ ewgt) {
    __shared__ float sm[HEADS][256];
    __shared__ float txv[HEADS][8];
    __shared__ int   txi[HEADS][8];
    __shared__ float tyv[HEADS][8];
    __shared__ int   tyi[HEADS][8];
    __shared__ float comb[HEADS][64];
    __shared__ float tfv[HEADS][8];
    __shared__ int   tfi[HEADS][8];
    const int t = blockIdx.x;
    const int head = threadIdx.x >> 6;
    const int lane = threadIdx.x & 63;

    const float4 v = *(const float4*)&sims[(size_t)t * 1024 + head * 256 + lane * 4];
    *(float4*)&sm[head][lane * 4] = v;

    const int isY = lane >= 32;
    const float* base = &sm[head][isY ? 128 : 0];
    const int gi = (lane * 4) - (isY ? 128 : 0);
    int r0 = 0, r1 = 0, r2 = 0, r3 = 0;
#pragma unroll
    for (int j = 0; j < 128; j += 4) {
        const float4 sv = *(const float4*)&base[j];
        r0 += (sv.x > v.x) | ((sv.x == v.x) & (j + 0 < gi + 0));
        r0 += (sv.y > v.x) | ((sv.y == v.x) & (j + 1 < gi + 0));
        r0 += (sv.z > v.x) | ((sv.z == v.x) & (j + 2 < gi + 0));
        r0 += (sv.w > v.x) | ((sv.w == v.x) & (j + 3 < gi + 0));
        r1 += (sv.x > v.y) | ((sv.x == v.y) & (j + 0 < gi + 1));
        r1 += (sv.y > v.y) | ((sv.y == v.y) & (j + 1 < gi + 1));
        r1 += (sv.z > v.y) | ((sv.z == v.y) & (j + 2 < gi + 1));
        r1 += (sv.w > v.y) | ((sv.w == v.y) & (j + 3 < gi + 1));
        r2 += (sv.x > v.z) | ((sv.x == v.z) & (j + 0 < gi + 2));
        r2 += (sv.y > v.z) | ((sv.y == v.z) & (j + 1 < gi + 2));
        r2 += (sv.z > v.z) | ((sv.z == v.z) & (j + 2 < gi + 2));
        r2 += (sv.w > v.z) | ((sv.w == v.z) & (j + 3 < gi + 2));
        r3 += (sv.x > v.w) | ((sv.x == v.w) & (j + 0 < gi + 3));
        r3 += (sv.y > v.w) | ((sv.y == v.w) & (j + 1 < gi + 3));
        r3 += (sv.z > v.w) | ((sv.z == v.w) & (j + 2 < gi + 3));
        r3 += (sv.w > v.w) | ((sv.w == v.w) & (j + 3 < gi + 3));
    }
    if (!isY) {
        if (r0 < TOPK) { txv[head][r0] = v.x; txi[head][r0] = gi + 0; }
        if (r1 < TOPK) { txv[head][r1] = v.y; txi[head][r1] = gi + 1; }
        if (r2 < TOPK) { txv[head][r2] = v.z; txi[head][r2] = gi + 2; }
        if (r3 < TOPK) { txv[head][r3] = v.w; txi[head][r3] = gi + 3; }
    } else {
        if (r0 < TOPK) { tyv[head][r0] = v.x; tyi[head][r0] = gi + 0; }
        if (r1 < TOPK) { tyv[head][r1] = v.y; tyi[head][r1] = gi + 1; }
        if (r2 < TOPK) { tyv[head][r2] = v.z; tyi[head][r2] = gi + 2; }
        if (r3 < TOPK) { tyv[head][r3] = v.w; tyi[head][r3] = gi + 3; }
    }

    const float cv = txv[head][lane >> 3] + tyv[head][lane & 7];
    const int   ci = txi[head][lane >> 3] * NKEYS + tyi[head][lane & 7];
    comb[head][lane] = cv;

    int cr = 0;
#pragma unroll
    for (int j = 0; j < 64; j += 4) {
        const float4 sv = *(const float4*)&comb[head][j];
        cr += (sv.x > cv) | ((sv.x == cv) & (j + 0 < lane));
        cr += (sv.y > cv) | ((sv.y == cv) & (j + 1 < lane));
        cr += (sv.z > cv) | ((sv.z == cv) & (j + 2 < lane));
        cr += (sv.w > cv) | ((sv.w == cv) & (j + 3 < lane));
    }
    if (cr < TOPK) { tfv[head][cr] = cv; tfi[head][cr] = ci; }

    float f[8];
#pragma unroll
    for (int j = 0; j < 8; ++j) f[j] = tfv[head][j];
    float mx = f[0];
#pragma unroll
    for (int j = 1; j < 8; ++j) mx = fmaxf(mx, f[j]);
    float ssum = 0.f;
#pragma unroll
    for (int j = 0; j < 8; ++j) ssum += expf(f[j] - mx);
    if (lane < 8) {
        eidx[t * 32 + head * 8 + lane] = tfi[head][lane];
        ewgt[t * 32 + head * 8 + lane] = expf(f[lane] - mx) / ssum;
    }
}

// ---------------- act[i] = silu(g[i]) * u[i], in-place on u -----------------
__global__ __launch_bounds__(256) void silu_mul_inplace(const ushort_t* __restrict__ g,
                                                        ushort_t* __restrict__ u) {
    const int i = blockIdx.x * 256 + threadIdx.x;
    const uint4 gv = ((const uint4*)g)[i];
    const uint4 uv = ((const uint4*)u)[i];
    const unsigned gw[4] = {gv.x, gv.y, gv.z, gv.w};
    const unsigned uw[4] = {uv.x, uv.y, uv.z, uv.w};
    unsigned ow[4];
#pragma unroll
    for (int j = 0; j < 4; ++j) {
        const float g0 = bf2f((ushort_t)(gw[j] & 0xffff));
        const float g1 = bf2f((ushort_t)(gw[j] >> 16));
        const float u0 = bf2f((ushort_t)(uw[j] & 0xffff));
        const float u1 = bf2f((ushort_t)(uw[j] >> 16));
        const float v0 = g0 / (1.f + __expf(-g0)) * u0;
        const float v1 = g1 / (1.f + __expf(-g1)) * u1;
        ow[j] = (unsigned)f2bf_rne(v0) | ((unsigned)f2bf_rne(v1) << 16);
    }
    ((uint4*)u)[i] = (uint4){ow[0], ow[1], ow[2], ow[3]};
}

// ---------------- FUSED: 128x128 gate/up GEMM + experts (fp8) [DELTA] -------
// 2560 blocks, pattern of 10: r10==4 -> gate GEMM id b/10 (0..255, 128x128
// tile: m0=(id>>4)*128, n0=(id&15)*128); r10==9 -> up GEMM; else expert
// token t = (b/10)*8 + r10 - (r10>4). GEMM is the proven <128,128,2,2,4,4>
// template geometry inlined; expert path byte-identical to R18.
__global__ __launch_bounds__(256) void fused3_kernel(
    const ushort_t* __restrict__ A,  const ushort_t* __restrict__ Bgate,
    const ushort_t* __restrict__ Bup, ushort_t* __restrict__ G,
    ushort_t* __restrict__ U,
    const float* __restrict__ hs, const unsigned* __restrict__ de_tab,
    const unsigned* __restrict__ ue_tab, const int* __restrict__ eidx,
    const float* __restrict__ ewgt, float* __restrict__ estate) {
    __shared__ __align__(16) char smem[16896];
    const int b = blockIdx.x;
    const int tid = threadIdx.x;
    const int w = tid >> 6, lane = tid & 63;
    const int r10 = b % 10;

    if (r10 == 4 || r10 == 9) {
        // -------- GEMM path: BM=128 BN=128 WR=2 WC=2 FM=4 FN=4 --------------
        const ushort_t* B = (r10 == 4) ? Bgate : Bup;
        ushort_t*      C  = (r10 == 4) ? G : U;
        const int id = b / 10;                        // 0..255
        const int m0 = (id >> 4) * 128, n0 = (id & 15) * 128;
        const int N = INTER, K = DIM;
        ushort_t* As = (ushort_t*)smem;               // 8 KB
        ushort_t* Bs = (ushort_t*)(smem + 8192);      // 8 KB
        const int wr = w >> 1, wc = w & 1;
        const int srow = (w << 4) + (lane >> 2);
        const int scol = (lane & 3) << 3;
        const ushort_t* Ag = &A[(size_t)(m0 + srow) * K + scol];
        const ushort_t* Bg = &B[(size_t)(n0 + srow) * K + scol];
        ushort_t* Al = &As[w << 9];
        ushort_t* Bl = &Bs[w << 9];
        const int frow = lane & 15;
        const int fcol = (lane >> 4) << 3;
        const ushort_t* Afr = &As[(size_t)(wr * 64 + frow) * 32 + fcol];
        const ushort_t* Bfr = &Bs[(size_t)(wc * 64 + frow) * 32 + fcol];

        f32x4 acc[4][4];
#pragma unroll
        for (int i = 0; i < 4; ++i)
#pragma unroll
            for (int j = 0; j < 4; ++j) acc[i][j] = (f32x4){0.f, 0.f, 0.f, 0.f};

        for (int k0 = 0; k0 < K; k0 += 32) {
            __syncthreads();
#pragma unroll
            for (int i = 0; i < 2; ++i)
                gload_lds16(Ag + (size_t)i * 64 * K + k0, Al + i * 2048);
#pragma unroll
            for (int i = 0; i < 2; ++i)
                gload_lds16(Bg + (size_t)i * 64 * K + k0, Bl + i * 2048);
            __syncthreads();

            bf16x8 af[4], bfv[4];
#pragma unroll
            for (int i = 0; i < 4; ++i) af[i] = *(const bf16x8*)(Afr + i * 512);
#pragma unroll
            for (int j = 0; j < 4; ++j) bfv[j] = *(const bf16x8*)(Bfr + j * 512);
#pragma unroll
            for (int i = 0; i < 4; ++i)
#pragma unroll
                for (int j = 0; j < 4; ++j)
                    acc[i][j] = __builtin_amdgcn_mfma_f32_16x16x32_bf16(
                        af[i], bfv[j], acc[i][j], 0, 0, 0);
        }

        const int crow0 = m0 + wr * 64 + ((lane >> 4) << 2);
        const int ccol0 = n0 + wc * 64 + (lane & 15);
#pragma unroll
        for (int i = 0; i < 4; ++i)
#pragma unroll
            for (int j = 0; j < 4; ++j)
#pragma unroll
                for (int r = 0; r < 4; ++r) {
                    const size_t off = (size_t)(crow0 + i * 16 + r) * N + ccol0 + j * 16;
                    C[off] = f2bf_rne(acc[i][j][r]);
                }
    } else {
        // -------- experts path: byte-identical to R18 (fp8 tables) ----------
        const int t = (b / 10) * 8 + r10 - (r10 > 4 ? 1 : 0);
        float4 (*partial)[256] = (float4(*)[256])smem;
        int*   eid = (int*)(smem + 16384);
        float* wl  = (float*)(smem + 16512);

        if (tid < 32) { eid[tid] = eidx[t * 32 + tid]; wl[tid] = ewgt[t * 32 + tid]; }

        const float4* hs4 = (const float4*)hs + (size_t)t * 256;
        float4 h[4];
#pragma unroll
        for (int i = 0; i < 4; ++i) h[i] = hs4[i * 64 + lane];
        __syncthreads();

        float4 acc[4];
#pragma unroll
        for (int i = 0; i < 4; ++i) acc[i] = (float4){0.f, 0.f, 0.f, 0.f};

        unsigned d[4], u[4], nd[4], nu[4];
        {
            const size_t bb = (size_t)eid[w * 8] * 256;
#pragma unroll
            for (int i = 0; i < 4; ++i) { d[i] = de_tab[bb + i * 64 + lane]; u[i] = ue_tab[bb + i * 64 + lane]; }
        }
#pragma unroll
        for (int jj = 0; jj < 8; ++jj) {
            if (jj < 7) {
                const size_t bb = (size_t)eid[w * 8 + jj + 1] * 256;
#pragma unroll
                for (int i = 0; i < 4; ++i) { nd[i] = de_tab[bb + i * 64 + lane]; nu[i] = ue_tab[bb + i * 64 + lane]; }
            }
            float s = 0.f;
#pragma unroll
            for (int i = 0; i < 4; ++i) {
                const f32x2 lo = __builtin_amdgcn_cvt_pk_f32_fp8((int)d[i], false);
                const f32x2 hi = __builtin_amdgcn_cvt_pk_f32_fp8((int)d[i], true);
                s += h[i].x * lo[0] + h[i].y * lo[1] + h[i].z * hi[0] + h[i].w * hi[1];
            }
#pragma unroll
            for (int m = 1; m < 64; m <<= 1) s += __shfl_xor(s, m);
            const float sr = s * 0.015625f;          // descale de (x64)
            const float c = (sr / (1.f + __expf(-sr))) * wl[w * 8 + jj];
#pragma unroll
            for (int i = 0; i < 4; ++i) {
                const f32x2 lo = __builtin_amdgcn_cvt_pk_f32_fp8((int)u[i], false);
                const f32x2 hi = __builtin_amdgcn_cvt_pk_f32_fp8((int)u[i], true);
                acc[i].x += c * lo[0]; acc[i].y += c * lo[1];
                acc[i].z += c * hi[0]; acc[i].w += c * hi[1];
            }
            if (jj < 7) {
#pragma unroll
                for (int i = 0; i < 4; ++i) { d[i] = nd[i]; u[i] = nu[i]; }
            }
        }

#pragma unroll
        for (int i = 0; i < 4; ++i) partial[w][i * 64 + lane] = acc[i];
        __syncthreads();

        const float4 p0 = partial[0][tid], p1 = partial[1][tid];
        const float4 p2 = partial[2][tid], p3 = partial[3][tid];
        float4 o;                                    // descale ue (x64)
        o.x = (p0.x + p1.x + p2.x + p3.x) * 0.015625f;
        o.y = (p0.y + p1.y + p2.y + p3.y) * 0.015625f;
        o.z = (p0.z + p1.z + p2.z + p3.z) * 0.015625f;
        o.w = (p0.w + p1.w + p2.w + p3.w) * 0.015625f;
        ((float4*)estate)[(size_t)t * 256 + tid] = o;
    }
}

// ---------------------------------------------------------------------------
extern "C" void kernel_launch(void* const* d_in, const int* in_sizes, int n_in,
                              void* d_out, int out_size, void* d_ws, size_t ws_size,
                              hipStream_t stream) {
    (void)in_sizes; (void)n_in; (void)out_size; (void)ws_size;
    const float* hidden = (const float*)d_in[0];
    const float* wq     = (const float*)d_in[1];
    const float* keys   = (const float*)d_in[2];
    const float* down_e = (const float*)d_in[3];
    const float* up_e   = (const float*)d_in[4];
    const float* wgate  = (const float*)d_in[5];
    const float* wup    = (const float*)d_in[6];
    const float* wdown  = (const float*)d_in[7];
    float* out = (float*)d_out;
    char* ws = (char*)d_ws;

    // workspace: EXACT round-17/18 layout (passed).
    ushort_t* hb  = (ushort_t*)(ws);                     // 4 MB
    ushort_t* wqb = (ushort_t*)(ws + (4u << 20));        // 0.5 MB
    ushort_t* wgb = (ushort_t*)(ws + (4608u << 10));     // 4 MB
    ushort_t* wub = (ushort_t*)(ws + (8704u << 10));     // 4 MB
    ushort_t* wdb = (ushort_t*)(ws + (12800u << 10));    // 4 MB
    float*    q   = (float*)   (ws + (16896u << 10));    // 2 MB (f32)
    ushort_t* act = (ushort_t*)(ws + (18944u << 10));    // 8 MB (sims, then u/act)
    float*   sims = (float*)act;                         // alias (pre-fused3)
    ushort_t* g   = (ushort_t*)(ws + (27136u << 10));    // 8 MB
    float*    wgt = (float*)   (ws + (35328u << 10));    // 0.25 MB
    int*     eidx = (int*)     (ws + (35584u << 10));    // 0.25 MB
    unsigned* deb = (unsigned*)(ws + 36700160u);         // 16 MB (fp8)
    unsigned* ueb = (unsigned*)(ws + 53477376u);         // 16 MB (fp8)
    float* estate = out;                                 // 8 MB, in d_out

    // 0) bf16 conversions (5 MFMA tensors)
    convert_all<<<4224, 256, 0, stream>>>(hidden, wq, wgate, wup, wdown,
                                          hb, wqb, wgb, wub, wdb);
    // 0b) expert tables -> fp8 e4m3 (x64), standalone streaming
    conv_tables<<<16384, 256, 0, stream>>>(down_e, up_e, deb, ueb);
    // 1) q = hidden @ wq^T -> f32
    mfma_gemm<64, 64, 2, 2, 2, 2, 0><<<dim3(4, 32), 256, 0, stream>>>(
        hb, wqb, nullptr, q, TOKENS, 256, DIM);
    // 2a) sims in f32 (keys-in-registers, token-tiled)
    sims_tiled<<<dim3(128, 4), 256, 0, stream>>>(q, keys, sims);
    // 2b) routing: rank-based select on f32 sims
    topk_select<<<TOKENS, 256, 0, stream>>>(sims, eidx, wgt);
    // 3+4+5 FUSED) 128x128 g/u GEMMs || experts (fp8 tables) -> out [DELTA]
    fused3_kernel<<<2560, 256, 0, stream>>>(
        hb, wgb, wub, g, act, hidden, deb, ueb, eidx, wgt, estate);
    // 4b) act = silu(g) * u, in-place on the u buffer
    silu_mul_inplace<<<2048, 256, 0, stream>>>(g, act);
    // 6) out = act @ wdown^T + out(=estate)
    mfma_gemm<64, 64, 2, 2, 2, 2, 2><<<dim3(16, 32), 256, 0, stream>>>(
        act, wdb, estate, out, TOKENS, DIM, INTER);
}

// Round 20
// 179.692 us; speedup vs baseline: 1.0336x; 1.0336x over previous
//
#include <hip/hip_runtime.h>
#include <hip/hip_bf16.h>
#include <math.h>

// ---------------------------------------------------------------------------
// DogeCDMoE round 20: REVERT to round-18 (best, 181.4us; R19's 128x128 tile
// regressed via VGPR coupling 80->108, occupancy 24->14.7%) + ONE delta:
// convert_all and conv_tables merge into a single conv_merged launch
// (matched-resource streaming blocks, bodies byte-identical) -- removes one
// dispatch boundary between two BW-bound kernels. All math unchanged ->
// absmax stays exactly 0.01367188.
// ---------------------------------------------------------------------------

#define TOKENS 2048
#define DIM    1024
#define INTER  2048
#define NKEYS  128
#define TOPK   8
#define HEADS  4

typedef unsigned short ushort_t;
typedef __attribute__((ext_vector_type(8))) short bf16x8;
typedef __attribute__((ext_vector_type(4))) float f32x4;
typedef __attribute__((ext_vector_type(2))) float f32x2;

__device__ __forceinline__ float bf2f(ushort_t u) {
    unsigned int x = (unsigned int)u << 16;
    float f; __builtin_memcpy(&f, &x, 4); return f;
}
__device__ __forceinline__ ushort_t f2bf_rne(float f) {
    unsigned int x; __builtin_memcpy(&x, &f, 4);
    x += 0x7fffu + ((x >> 16) & 1u);
    return (ushort_t)(x >> 16);
}
__device__ __forceinline__ void gload_lds16(const void* g, void* l) {
    __builtin_amdgcn_global_load_lds(
        (const __attribute__((address_space(1))) unsigned int*)g,
        (__attribute__((address_space(3))) unsigned int*)l, 16, 0, 0);
}

// ---------------- merged streaming conversions [THE DELTA] ------------------
// blocks [0, 4224): f32->bf16 for the 5 MFMA tensors (convert_all body).
// blocks [4224, 4224+16384): expert tables f32->fp8 e4m3 x64 (conv_tables
// body). Both bodies byte-identical to R18; matched resource class.
__global__ __launch_bounds__(256) void conv_merged(
    const float* __restrict__ h,  const float* __restrict__ wq,
    const float* __restrict__ wg, const float* __restrict__ wu,
    const float* __restrict__ wd,
    const float* __restrict__ de_f32, const float* __restrict__ ue_f32,
    ushort_t* __restrict__ hb,  ushort_t* __restrict__ wqb,
    ushort_t* __restrict__ wgb, ushort_t* __restrict__ wub,
    ushort_t* __restrict__ wdb,
    unsigned* __restrict__ deb, unsigned* __restrict__ ueb) {
    const int blk = blockIdx.x;
    if (blk < 4224) {
        const int i = blk * 256 + threadIdx.x;
        const float* src; ushort_t* dst; int off;
        if      (i <  262144) { src = h;  dst = hb;  off = i; }
        else if (i <  294912) { src = wq; dst = wqb; off = i - 262144; }
        else if (i <  557056) { src = wg; dst = wgb; off = i - 294912; }
        else if (i <  819200) { src = wu; dst = wub; off = i - 557056; }
        else                  { src = wd; dst = wdb; off = i - 819200; }
        const float4* p = (const float4*)src + (size_t)off * 2;
        const float4 a = p[0], b = p[1];
        uint4 o;
        o.x = (unsigned)f2bf_rne(a.x) | ((unsigned)f2bf_rne(a.y) << 16);
        o.y = (unsigned)f2bf_rne(a.z) | ((unsigned)f2bf_rne(a.w) << 16);
        o.z = (unsigned)f2bf_rne(b.x) | ((unsigned)f2bf_rne(b.y) << 16);
        o.w = (unsigned)f2bf_rne(b.z) | ((unsigned)f2bf_rne(b.w) << 16);
        ((uint4*)dst)[off] = o;
    } else {
        const int id = blk - 4224;                   // 0..16383
        const float* src = (id < 8192) ? de_f32 : ue_f32;
        unsigned*    dst = (id < 8192) ? deb : ueb;
        const size_t eoff = (size_t)(id & 8191) * 2048 + threadIdx.x * 8;
        const float4* p = (const float4*)(src + eoff);
        const float4 a = p[0], b = p[1];
        int w0 = 0, w1 = 0;
        w0 = __builtin_amdgcn_cvt_pk_fp8_f32(a.x * 64.f, a.y * 64.f, w0, false);
        w0 = __builtin_amdgcn_cvt_pk_fp8_f32(a.z * 64.f, a.w * 64.f, w0, true);
        w1 = __builtin_amdgcn_cvt_pk_fp8_f32(b.x * 64.f, b.y * 64.f, w1, false);
        w1 = __builtin_amdgcn_cvt_pk_fp8_f32(b.z * 64.f, b.w * 64.f, w1, true);
        *(uint2*)((char*)dst + eoff) = (uint2){(unsigned)w0, (unsigned)w1};
    }
}

// ---------------- bf16 MFMA GEMM: C[M,N] = A[M,K] @ B[N,K]^T ----------------
// EPI 0: f32 = acc | 2: f32 = acc+extra_f32 (Cout may == extra) | 3: bf16
template<int BM, int BN, int WR, int WC, int FM, int FN, int EPI>
__global__ __launch_bounds__(256) void mfma_gemm(const ushort_t* __restrict__ A,
                                                 const ushort_t* __restrict__ B,
                                                 const void* __restrict__ extra,
                                                 void* __restrict__ Cout,
                                                 int M, int N, int K) {
    static_assert(WR * WC == 4 && WR * FM * 16 == BM && WC * FN * 16 == BN, "geom");
    __shared__ ushort_t As[BM * 32];
    __shared__ ushort_t Bs[BN * 32];
    const int tid = threadIdx.x;
    const int w = tid >> 6, lane = tid & 63;
    const int wr = w / WC, wc = w % WC;
    const int m0 = blockIdx.y * BM, n0 = blockIdx.x * BN;

    const int srow = (w << 4) + (lane >> 2);
    const int scol = (lane & 3) << 3;
    const ushort_t* Ag = &A[(size_t)(m0 + srow) * K + scol];
    const ushort_t* Bg = &B[(size_t)(n0 + srow) * K + scol];
    ushort_t* Al = &As[w << 9];
    ushort_t* Bl = &Bs[w << 9];

    const int frow = lane & 15;
    const int fcol = (lane >> 4) << 3;
    const ushort_t* Afr = &As[(size_t)(wr * FM * 16 + frow) * 32 + fcol];
    const ushort_t* Bfr = &Bs[(size_t)(wc * FN * 16 + frow) * 32 + fcol];

    f32x4 acc[FM][FN];
#pragma unroll
    for (int i = 0; i < FM; ++i)
#pragma unroll
        for (int j = 0; j < FN; ++j) acc[i][j] = (f32x4){0.f, 0.f, 0.f, 0.f};

    for (int k0 = 0; k0 < K; k0 += 32) {
        __syncthreads();
#pragma unroll
        for (int i = 0; i < BM / 64; ++i)
            gload_lds16(Ag + (size_t)i * 64 * K + k0, Al + i * 2048);
#pragma unroll
        for (int i = 0; i < BN / 64; ++i)
            gload_lds16(Bg + (size_t)i * 64 * K + k0, Bl + i * 2048);
        __syncthreads();

        bf16x8 af[FM], bfv[FN];
#pragma unroll
        for (int i = 0; i < FM; ++i) af[i] = *(const bf16x8*)(Afr + i * 512);
#pragma unroll
        for (int j = 0; j < FN; ++j) bfv[j] = *(const bf16x8*)(Bfr + j * 512);
#pragma unroll
        for (int i = 0; i < FM; ++i)
#pragma unroll
            for (int j = 0; j < FN; ++j)
                acc[i][j] = __builtin_amdgcn_mfma_f32_16x16x32_bf16(
                    af[i], bfv[j], acc[i][j], 0, 0, 0);
    }

    const int crow0 = m0 + wr * FM * 16 + ((lane >> 4) << 2);
    const int ccol0 = n0 + wc * FN * 16 + (lane & 15);
#pragma unroll
    for (int i = 0; i < FM; ++i)
#pragma unroll
        for (int j = 0; j < FN; ++j)
#pragma unroll
            for (int r = 0; r < 4; ++r) {
                const size_t off = (size_t)(crow0 + i * 16 + r) * N + ccol0 + j * 16;
                float v = acc[i][j][r];
                if (EPI == 2) {
                    ((float*)Cout)[off] = v + ((const float*)extra)[off];
                } else if (EPI == 3) {
                    ((ushort_t*)Cout)[off] = f2bf_rne(v);
                } else {
                    ((float*)Cout)[off] = v;
                }
            }
}

// ---------------- sims_tiled: key column in registers (R18-verified) --------
__global__ __launch_bounds__(256) void sims_tiled(const float* __restrict__ q,
                                                  const float* __restrict__ keys,
                                                  float* __restrict__ sims) {
    const int head = blockIdx.y;
    const int t0 = blockIdx.x * 16;
    const int p = threadIdx.x >> 7, k = threadIdx.x & 127;

    const float4* kc = (const float4*)&keys[(size_t)(((head << 7) | k) * 2 + p) * 32];
    float4 kv[8];
#pragma unroll
    for (int n = 0; n < 8; ++n) kv[n] = kc[n];

#pragma unroll 4
    for (int tt = 0; tt < 16; ++tt) {
        const int t = t0 + tt;
        const float4* qv = (const float4*)&q[(size_t)t * 256 + p * 128 + head * 32];
        float s = 0.f;
#pragma unroll
        for (int n = 0; n < 8; ++n) {
            const float4 a = qv[n], b = kv[n];
            s += a.x * b.x + a.y * b.y + a.z * b.z + a.w * b.w;
        }
        sims[(size_t)t * 1024 + head * 256 + p * 128 + k] = s;
    }
}

// ---------------- topk_select: rank-based on f32 sims (R16-18 verified) -----
__global__ __launch_bounds__(256) void topk_select(const float* __restrict__ sims,
                                                   int* __restrict__ eidx,
                                                   float* __restrict__ ewgt) {
    __shared__ float sm[HEADS][256];
    __shared__ float txv[HEADS][8];
    __shared__ int   txi[HEADS][8];
    __shared__ float tyv[HEADS][8];
    __shared__ int   tyi[HEADS][8];
    __shared__ float comb[HEADS][64];
    __shared__ float tfv[HEADS][8];
    __shared__ int   tfi[HEADS][8];
    const int t = blockIdx.x;
    const int head = threadIdx.x >> 6;
    const int lane = threadIdx.x & 63;

    const float4 v = *(const float4*)&sims[(size_t)t * 1024 + head * 256 + lane * 4];
    *(float4*)&sm[head][lane * 4] = v;

    const int isY = lane >= 32;
    const float* base = &sm[head][isY ? 128 : 0];
    const int gi = (lane * 4) - (isY ? 128 : 0);
    int r0 = 0, r1 = 0, r2 = 0, r3 = 0;
#pragma unroll
    for (int j = 0; j < 128; j += 4) {
        const float4 sv = *(const float4*)&base[j];
        r0 += (sv.x > v.x) | ((sv.x == v.x) & (j + 0 < gi + 0));
        r0 += (sv.y > v.x) | ((sv.y == v.x) & (j + 1 < gi + 0));
        r0 += (sv.z > v.x) | ((sv.z == v.x) & (j + 2 < gi + 0));
        r0 += (sv.w > v.x) | ((sv.w == v.x) & (j + 3 < gi + 0));
        r1 += (sv.x > v.y) | ((sv.x == v.y) & (j + 0 < gi + 1));
        r1 += (sv.y > v.y) | ((sv.y == v.y) & (j + 1 < gi + 1));
        r1 += (sv.z > v.y) | ((sv.z == v.y) & (j + 2 < gi + 1));
        r1 += (sv.w > v.y) | ((sv.w == v.y) & (j + 3 < gi + 1));
        r2 += (sv.x > v.z) | ((sv.x == v.z) & (j + 0 < gi + 2));
        r2 += (sv.y > v.z) | ((sv.y == v.z) & (j + 1 < gi + 2));
        r2 += (sv.z > v.z) | ((sv.z == v.z) & (j + 2 < gi + 2));
        r2 += (sv.w > v.z) | ((sv.w == v.z) & (j + 3 < gi + 2));
        r3 += (sv.x > v.w) | ((sv.x == v.w) & (j + 0 < gi + 3));
        r3 += (sv.y > v.w) | ((sv.y == v.w) & (j + 1 < gi + 3));
        r3 += (sv.z > v.w) | ((sv.z == v.w) & (j + 2 < gi + 3));
        r3 += (sv.w > v.w) | ((sv.w == v.w) & (j + 3 < gi + 3));
    }
    if (!isY) {
        if (r0 < TOPK) { txv[head][r0] = v.x; txi[head][r0] = gi + 0; }
        if (r1 < TOPK) { txv[head][r1] = v.y; txi[head][r1] = gi + 1; }
        if (r2 < TOPK) { txv[head][r2] = v.z; txi[head][r2] = gi + 2; }
        if (r3 < TOPK) { txv[head][r3] = v.w; txi[head][r3] = gi + 3; }
    } else {
        if (r0 < TOPK) { tyv[head][r0] = v.x; tyi[head][r0] = gi + 0; }
        if (r1 < TOPK) { tyv[head][r1] = v.y; tyi[head][r1] = gi + 1; }
        if (r2 < TOPK) { tyv[head][r2] = v.z; tyi[head][r2] = gi + 2; }
        if (r3 < TOPK) { tyv[head][r3] = v.w; tyi[head][r3] = gi + 3; }
    }

    const float cv = txv[head][lane >> 3] + tyv[head][lane & 7];
    const int   ci = txi[head][lane >> 3] * NKEYS + tyi[head][lane & 7];
    comb[head][lane] = cv;

    int cr = 0;
#pragma unroll
    for (int j = 0; j < 64; j += 4) {
        const float4 sv = *(const float4*)&comb[head][j];
        cr += (sv.x > cv) | ((sv.x == cv) & (j + 0 < lane));
        cr += (sv.y > cv) | ((sv.y == cv) & (j + 1 < lane));
        cr += (sv.z > cv) | ((sv.z == cv) & (j + 2 < lane));
        cr += (sv.w > cv) | ((sv.w == cv) & (j + 3 < lane));
    }
    if (cr < TOPK) { tfv[head][cr] = cv; tfi[head][cr] = ci; }

    float f[8];
#pragma unroll
    for (int j = 0; j < 8; ++j) f[j] = tfv[head][j];
    float mx = f[0];
#pragma unroll
    for (int j = 1; j < 8; ++j) mx = fmaxf(mx, f[j]);
    float ssum = 0.f;
#pragma unroll
    for (int j = 0; j < 8; ++j) ssum += expf(f[j] - mx);
    if (lane < 8) {
        eidx[t * 32 + head * 8 + lane] = tfi[head][lane];
        ewgt[t * 32 + head * 8 + lane] = expf(f[lane] - mx) / ssum;
    }
}

// ---------------- act[i] = silu(g[i]) * u[i], in-place on u -----------------
__global__ __launch_bounds__(256) void silu_mul_inplace(const ushort_t* __restrict__ g,
                                                        ushort_t* __restrict__ u) {
    const int i = blockIdx.x * 256 + threadIdx.x;
    const uint4 gv = ((const uint4*)g)[i];
    const uint4 uv = ((const uint4*)u)[i];
    const unsigned gw[4] = {gv.x, gv.y, gv.z, gv.w};
    const unsigned uw[4] = {uv.x, uv.y, uv.z, uv.w};
    unsigned ow[4];
#pragma unroll
    for (int j = 0; j < 4; ++j) {
        const float g0 = bf2f((ushort_t)(gw[j] & 0xffff));
        const float g1 = bf2f((ushort_t)(gw[j] >> 16));
        const float u0 = bf2f((ushort_t)(uw[j] & 0xffff));
        const float u1 = bf2f((ushort_t)(uw[j] >> 16));
        const float v0 = g0 / (1.f + __expf(-g0)) * u0;
        const float v1 = g1 / (1.f + __expf(-g1)) * u1;
        ow[j] = (unsigned)f2bf_rne(v0) | ((unsigned)f2bf_rne(v1) << 16);
    }
    ((uint4*)u)[i] = (uint4){ow[0], ow[1], ow[2], ow[3]};
}

// ---------------- FUSED: 64x128 gate/up GEMM + experts (fp8) [R18 exact] ----
__global__ __launch_bounds__(256) void fused3_kernel(
    const ushort_t* __restrict__ A,  const ushort_t* __restrict__ Bgate,
    const ushort_t* __restrict__ Bup, ushort_t* __restrict__ G,
    ushort_t* __restrict__ U,
    const float* __restrict__ hs, const unsigned* __restrict__ de_tab,
    const unsigned* __restrict__ ue_tab, const int* __restrict__ eidx,
    const float* __restrict__ ewgt, float* __restrict__ estate) {
    __shared__ __align__(16) char smem[16896];
    const int b = blockIdx.x;
    const int tid = threadIdx.x;
    const int w = tid >> 6, lane = tid & 63;
    const int r6 = b % 6;

    if (r6 == 2 || r6 == 5) {
        const ushort_t* B = (r6 == 2) ? Bgate : Bup;
        ushort_t*      C  = (r6 == 2) ? G : U;
        const int id = b / 6;
        const int m0 = (id >> 4) * 64, n0 = (id & 15) * 128;
        const int N = INTER, K = DIM;
        ushort_t* As = (ushort_t*)smem;
        ushort_t* Bs = (ushort_t*)(smem + 4096);
        const int wc = w;
        const int srow = (w << 4) + (lane >> 2);
        const int scol = (lane & 3) << 3;
        const ushort_t* Ag = &A[(size_t)(m0 + srow) * K + scol];
        const ushort_t* Bg = &B[(size_t)(n0 + srow) * K + scol];
        ushort_t* Al = &As[w << 9];
        ushort_t* Bl = &Bs[w << 9];
        const int frow = lane & 15;
        const int fcol = (lane >> 4) << 3;
        const ushort_t* Afr = &As[(size_t)frow * 32 + fcol];
        const ushort_t* Bfr = &Bs[(size_t)(wc * 32 + frow) * 32 + fcol];

        f32x4 acc[4][2];
#pragma unroll
        for (int i = 0; i < 4; ++i)
#pragma unroll
            for (int j = 0; j < 2; ++j) acc[i][j] = (f32x4){0.f, 0.f, 0.f, 0.f};

        for (int k0 = 0; k0 < K; k0 += 32) {
            __syncthreads();
            gload_lds16(Ag + k0, Al);
#pragma unroll
            for (int i = 0; i < 2; ++i)
                gload_lds16(Bg + (size_t)i * 64 * K + k0, Bl + i * 2048);
            __syncthreads();

            bf16x8 af[4], bfv[2];
#pragma unroll
            for (int i = 0; i < 4; ++i) af[i] = *(const bf16x8*)(Afr + i * 512);
#pragma unroll
            for (int j = 0; j < 2; ++j) bfv[j] = *(const bf16x8*)(Bfr + j * 512);
#pragma unroll
            for (int i = 0; i < 4; ++i)
#pragma unroll
                for (int j = 0; j < 2; ++j)
                    acc[i][j] = __builtin_amdgcn_mfma_f32_16x16x32_bf16(
                        af[i], bfv[j], acc[i][j], 0, 0, 0);
        }

        const int crow0 = m0 + ((lane >> 4) << 2);
        const int ccol0 = n0 + wc * 32 + (lane & 15);
#pragma unroll
        for (int i = 0; i < 4; ++i)
#pragma unroll
            for (int j = 0; j < 2; ++j)
#pragma unroll
                for (int r = 0; r < 4; ++r) {
                    const size_t off = (size_t)(crow0 + i * 16 + r) * N + ccol0 + j * 16;
                    C[off] = f2bf_rne(acc[i][j][r]);
                }
    } else {
        const int t = (b / 6) * 4 + r6 - (r6 > 2 ? 1 : 0);
        float4 (*partial)[256] = (float4(*)[256])smem;
        int*   eid = (int*)(smem + 16384);
        float* wl  = (float*)(smem + 16512);

        if (tid < 32) { eid[tid] = eidx[t * 32 + tid]; wl[tid] = ewgt[t * 32 + tid]; }

        const float4* hs4 = (const float4*)hs + (size_t)t * 256;
        float4 h[4];
#pragma unroll
        for (int i = 0; i < 4; ++i) h[i] = hs4[i * 64 + lane];
        __syncthreads();

        float4 acc[4];
#pragma unroll
        for (int i = 0; i < 4; ++i) acc[i] = (float4){0.f, 0.f, 0.f, 0.f};

        unsigned d[4], u[4], nd[4], nu[4];
        {
            const size_t bb = (size_t)eid[w * 8] * 256;
#pragma unroll
            for (int i = 0; i < 4; ++i) { d[i] = de_tab[bb + i * 64 + lane]; u[i] = ue_tab[bb + i * 64 + lane]; }
        }
#pragma unroll
        for (int jj = 0; jj < 8; ++jj) {
            if (jj < 7) {
                const size_t bb = (size_t)eid[w * 8 + jj + 1] * 256;
#pragma unroll
                for (int i = 0; i < 4; ++i) { nd[i] = de_tab[bb + i * 64 + lane]; nu[i] = ue_tab[bb + i * 64 + lane]; }
            }
            float s = 0.f;
#pragma unroll
            for (int i = 0; i < 4; ++i) {
                const f32x2 lo = __builtin_amdgcn_cvt_pk_f32_fp8((int)d[i], false);
                const f32x2 hi = __builtin_amdgcn_cvt_pk_f32_fp8((int)d[i], true);
                s += h[i].x * lo[0] + h[i].y * lo[1] + h[i].z * hi[0] + h[i].w * hi[1];
            }
#pragma unroll
            for (int m = 1; m < 64; m <<= 1) s += __shfl_xor(s, m);
            const float sr = s * 0.015625f;          // descale de (x64)
            const float c = (sr / (1.f + __expf(-sr))) * wl[w * 8 + jj];
#pragma unroll
            for (int i = 0; i < 4; ++i) {
                const f32x2 lo = __builtin_amdgcn_cvt_pk_f32_fp8((int)u[i], false);
                const f32x2 hi = __builtin_amdgcn_cvt_pk_f32_fp8((int)u[i], true);
                acc[i].x += c * lo[0]; acc[i].y += c * lo[1];
                acc[i].z += c * hi[0]; acc[i].w += c * hi[1];
            }
            if (jj < 7) {
#pragma unroll
                for (int i = 0; i < 4; ++i) { d[i] = nd[i]; u[i] = nu[i]; }
            }
        }

#pragma unroll
        for (int i = 0; i < 4; ++i) partial[w][i * 64 + lane] = acc[i];
        __syncthreads();

        const float4 p0 = partial[0][tid], p1 = partial[1][tid];
        const float4 p2 = partial[2][tid], p3 = partial[3][tid];
        float4 o;                                    // descale ue (x64)
        o.x = (p0.x + p1.x + p2.x + p3.x) * 0.015625f;
        o.y = (p0.y + p1.y + p2.y + p3.y) * 0.015625f;
        o.z = (p0.z + p1.z + p2.z + p3.z) * 0.015625f;
        o.w = (p0.w + p1.w + p2.w + p3.w) * 0.015625f;
        ((float4*)estate)[(size_t)t * 256 + tid] = o;
    }
}

// ---------------------------------------------------------------------------
extern "C" void kernel_launch(void* const* d_in, const int* in_sizes, int n_in,
                              void* d_out, int out_size, void* d_ws, size_t ws_size,
                              hipStream_t stream) {
    (void)in_sizes; (void)n_in; (void)out_size; (void)ws_size;
    const float* hidden = (const float*)d_in[0];
    const float* wq     = (const float*)d_in[1];
    const float* keys   = (const float*)d_in[2];
    const float* down_e = (const float*)d_in[3];
    const float* up_e   = (const float*)d_in[4];
    const float* wgate  = (const float*)d_in[5];
    const float* wup    = (const float*)d_in[6];
    const float* wdown  = (const float*)d_in[7];
    float* out = (float*)d_out;
    char* ws = (char*)d_ws;

    // workspace: EXACT round-17/18 layout (passed).
    ushort_t* hb  = (ushort_t*)(ws);                     // 4 MB
    ushort_t* wqb = (ushort_t*)(ws + (4u << 20));        // 0.5 MB
    ushort_t* wgb = (ushort_t*)(ws + (4608u << 10));     // 4 MB
    ushort_t* wub = (ushort_t*)(ws + (8704u << 10));     // 4 MB
    ushort_t* wdb = (ushort_t*)(ws + (12800u << 10));    // 4 MB
    float*    q   = (float*)   (ws + (16896u << 10));    // 2 MB (f32)
    ushort_t* act = (ushort_t*)(ws + (18944u << 10));    // 8 MB (sims, then u/act)
    float*   sims = (float*)act;                         // alias (pre-fused3)
    ushort_t* g   = (ushort_t*)(ws + (27136u << 10));    // 8 MB
    float*    wgt = (float*)   (ws + (35328u << 10));    // 0.25 MB
    int*     eidx = (int*)     (ws + (35584u << 10));    // 0.25 MB
    unsigned* deb = (unsigned*)(ws + 36700160u);         // 16 MB (fp8)
    unsigned* ueb = (unsigned*)(ws + 53477376u);         // 16 MB (fp8)
    float* estate = out;                                 // 8 MB, in d_out

    // 0) ALL conversions in one merged streaming launch [THE DELTA]
    conv_merged<<<20608, 256, 0, stream>>>(hidden, wq, wgate, wup, wdown,
                                           down_e, up_e,
                                           hb, wqb, wgb, wub, wdb, deb, ueb);
    // 1) q = hidden @ wq^T -> f32
    mfma_gemm<64, 64, 2, 2, 2, 2, 0><<<dim3(4, 32), 256, 0, stream>>>(
        hb, wqb, nullptr, q, TOKENS, 256, DIM);
    // 2a) sims in f32 (keys-in-registers, token-tiled)
    sims_tiled<<<dim3(128, 4), 256, 0, stream>>>(q, keys, sims);
    // 2b) routing: rank-based select on f32 sims
    topk_select<<<TOKENS, 256, 0, stream>>>(sims, eidx, wgt);
    // 3+4+5 FUSED) 64x128 g/u GEMMs || experts (fp8 tables) -> out
    fused3_kernel<<<3072, 256, 0, stream>>>(
        hb, wgb, wub, g, act, hidden, deb, ueb, eidx, wgt, estate);
    // 4b) act = silu(g) * u, in-place on the u buffer
    silu_mul_inplace<<<2048, 256, 0, stream>>>(g, act);
    // 6) out = act @ wdown^T + out(=estate)
    mfma_gemm<64, 64, 2, 2, 2, 2, 2><<<dim3(16, 32), 256, 0, stream>>>(
        act, wdb, estate, out, TOKENS, DIM, INTER);
}